// Round 23
// baseline (208.749 us; speedup 1.0000x reference)
//
#include <hip/hip_runtime.h>
#include <stdint.h>

#define NSITE 512
#define DD    64
#define NB    64
#define NO    10
#define NSEG  16
#define SEGLEN 32
#define SLAB_BYTES 32768   // slab stride: front 16 KB image, back 16 KB P
#define PACK_BYTES 16384
#define WS_NEED (2u * NSITE * SLAB_BYTES)   // 32 MB

typedef short bf16x8 __attribute__((ext_vector_type(8)));
typedef float f32x16 __attribute__((ext_vector_type(16)));

// trunc-pack two f32 -> packed bf16 dword (lo=a, hi=b) in ONE v_perm_b32
__device__ __forceinline__ uint32_t pk2(float a, float b) {
    return __builtin_amdgcn_perm(__float_as_uint(b), __float_as_uint(a), 0x07060302);
}

// packed f32 pair multiply: one VOP3P instruction
__device__ __forceinline__ float2 pkmul2(float2 a, float2 b) {
    float2 r;
    asm("v_pk_mul_f32 %0, %1, %2" : "=v"(r) : "v"(a), "v"(b));
    return r;
}

// ---------------------------------------------------------------------------
// Pack W fp32 [s][l][r][w] -> bf16 K-stacked A-operand image.  r13 body,
// r21 src/dst split (dst = d_ws when it fits; in-place fallback).
// ---------------------------------------------------------------------------
__global__ __launch_bounds__(256) void pack_kernel(const float* wlsrc,
                                                   const float* wrsrc,
                                                   char* dl, char* dr) {
    const int g = blockIdx.x;                 // 0..1023
    const int right = (g >= NSITE) ? 1 : 0;
    const int s = right ? g - NSITE : g;
    const float* src = (right ? wrsrc : wlsrc) + (size_t)s * (SLAB_BYTES / 4);
    char* dst = (right ? dr : dl) + (size_t)s * SLAB_BYTES;

    __shared__ float2 st[DD * 65];            // padded [l][r] (w0,w1) pairs
    const float4* src4 = (const float4*)src;  // 16B/lane loads
    for (int e4 = threadIdx.x; e4 < DD * DD / 2; e4 += 256) {
        const float4 v = src4[e4];
        const int e = e4 * 2;                 // e even -> same padded row for e, e+1
        float2* d = &st[(e >> 6) * 65 + (e & 63)];
        d[0] = make_float2(v.x, v.y);
        d[1] = make_float2(v.z, v.w);
    }
    __syncthreads();

    uint32_t* out = (uint32_t*)dst;           // front 16 KB = 4096 dwords
    #pragma unroll
    for (int rr = 0; rr < 16; ++rr) {
        const int od = rr * 256 + threadIdx.x;        // coalesced writes
        const int chunk = od >> 8, i = chunk >> 3, sk = chunk & 7;
        const int H = (od >> 7) & 1, m5 = (od >> 2) & 31, d = od & 3;
        const int m = 32 * i + m5, k = 8 * sk + 4 * H + d;
        const float2 a = right ? st[m * 65 + k] : st[k * 65 + m];
        out[od] = pk2(a.x, a.y);              // lo = w0, hi = w1
    }
}

__device__ __forceinline__ void dma16(const void* gp, void* lp) {
    __builtin_amdgcn_global_load_lds(
        (const __attribute__((address_space(1))) uint32_t*)gp,
        (__attribute__((address_space(3))) uint32_t*)lp, 16, 0, 0);
}

// ---------------------------------------------------------------------------
// Stage 1 -- BARRIER-FREE rewrite (the one structural element all six
// failed theories shared was the 4-wave barrier; r12 showed barrier COUNT
// is irrelevant, this tests barrier EXISTENCE).  One 64-thread block = one
// (side,seg,b) chain; wave-private 2-slot ring (32 KB -> 5 blocks/CU); each
// wave stages ALL 16 chunks itself.  Sync is per-wave counters only:
//   vmcnt(16) [site t done, t+1 in flight] -> af := ds_read slot[t&1] (regs)
//   -> lgkmcnt(0) (+sched_barrier fences, rule #18) -> re-issue slot[t&1]
//   with site t+2 -> extract bfa / MFMA from regs.
// x broadcast via __shfl from lane-t register (no LDS).  Dummy clamped
// issues at t>=30 rewrite identical bytes into already-read slots.  setprio
// kept: waves are now independently phased (T5's favorable regime).
// Math identical to r20 (absmax 0.0 form): bfa extract + chained acc.
// ---------------------------------------------------------------------------
__global__ __launch_bounds__(64, 2) void stage1_kernel(
        const float* __restrict__ x, char* __restrict__ dl, char* __restrict__ dr) {
    const int pb   = blockIdx.x;                  // physical 0..2047
    const int bid  = (pb & 7) * 256 + (pb >> 3);  // logical; each (side,seg) group
    const int side = bid >> 10;                   // of 64 blocks lands on ONE XCD
    const int seg  = (bid >> 6) & 15;
    const int b    = bid & 63;
    const int lane = threadIdx.x;                 // 0..63
    const int m5   = lane & 31;
    const int H    = lane >> 5;

    __shared__ __align__(16) char ring[2][PACK_BYTES];   // 32 KB, wave-private

    char* wbuf = side ? dr : dl;

    // x pairs for this wave's 32 sites, held in lanes 0..31 (no LDS)
    float2 xreg = make_float2(0.f, 0.f);
    if (lane < SEGLEN) {
        const float2* xp = ((const float2*)x) + (size_t)b * 1024 + (side ? NSITE : 0);
        const int sg = seg * SEGLEN + (side ? SEGLEN - 1 - lane : lane);
        xreg = xp[sg];
    }

    auto siteAddr = [&](int t) -> const char* {
        const int sg = seg * SEGLEN + (side ? SEGLEN - 1 - t : t);
        return wbuf + (size_t)sg * SLAB_BYTES;
    };

    // prologue: sites 0,1 -> slots 0,1  (32 loads outstanding)
    #pragma unroll
    for (int t0 = 0; t0 < 2; ++t0) {
        const char* sb = siteAddr(t0);
        #pragma unroll
        for (int c = 0; c < 16; ++c)
            dma16(sb + c * 1024 + lane * 16, ring[t0] + c * 1024);
    }

    // acc := Identity (C/D layout: row=(q&3)+8(q>>2)+4H, col=32j+m5)
    f32x16 acc[2][2];
    #pragma unroll
    for (int i = 0; i < 2; ++i)
        #pragma unroll
        for (int j = 0; j < 2; ++j)
            #pragma unroll
            for (int q = 0; q < 16; ++q) {
                const int row = (q & 3) + 8 * (q >> 2) + 4 * H;
                acc[i][j][q] = (i == j && row == m5) ? 1.f : 0.f;
            }

    f32x16 zf;
    #pragma unroll
    for (int q = 0; q < 16; ++q) zf[q] = 0.f;

    union BU { bf16x8 v; uint32_t w[4]; };

    for (int t = 0; t < SEGLEN; ++t) {
        // own site-t chunks in LDS (site t+1's 16 remain in flight)
        asm volatile("s_waitcnt vmcnt(16)" ::: "memory");
        __builtin_amdgcn_sched_barrier(0);

        // A-fragments -> registers (frees the slot after lgkm drain)
        const char* rb = ring[t & 1];
        uint4 af[2][8];
        #pragma unroll
        for (int i = 0; i < 2; ++i)
            #pragma unroll
            for (int sk = 0; sk < 8; ++sk)
                af[i][sk] = *(const uint4*)(rb + (i * 8 + sk) * 1024 + lane * 16);
        __builtin_amdgcn_sched_barrier(0);
        asm volatile("s_waitcnt lgkmcnt(0)" ::: "memory");   // reads retired
        __builtin_amdgcn_sched_barrier(0);

        // re-issue this slot with site t+2 (clamped dummy re-writes same bytes)
        {
            int t2 = t + 2; if (t2 > SEGLEN - 1) t2 = SEGLEN - 1;
            const char* sb = siteAddr(t2);
            char* lb = ring[t & 1];
            #pragma unroll
            for (int c = 0; c < 16; ++c)
                dma16(sb + c * 1024 + lane * 16, lb + c * 1024);
        }

        // x for this site, broadcast from lane t
        const float2 xv = make_float2(__shfl(xreg.x, t, 64), __shfl(xreg.y, t, 64));
        const float2 xx = make_float2(xv.x, xv.x);
        const float2 xy = make_float2(xv.y, xv.y);

        // per-sk: extract B-fragment from acc, then MFMA (af in regs; bfa
        // reads old acc values before the chain overwrites them -- SSA)
        __builtin_amdgcn_s_setprio(1);
        #pragma unroll
        for (int sk = 0; sk < 8; ++sk) {
            const int mi = sk >> 2, qb = 4 * (sk & 3);
            BU bfa[2];
            #pragma unroll
            for (int j = 0; j < 2; ++j)
                #pragma unroll
                for (int dp = 0; dp < 2; ++dp) {
                    const float2 v01 = make_float2(acc[mi][j][qb + 2 * dp],
                                                   acc[mi][j][qb + 2 * dp + 1]);
                    const float2 pa = pkmul2(xx, v01);   // {x0*v0, x0*v1}
                    const float2 pb = pkmul2(xy, v01);   // {x1*v0, x1*v1}
                    bfa[j].w[2 * dp + 0] = pk2(pa.x, pb.x);  // kap even: x0
                    bfa[j].w[2 * dp + 1] = pk2(pa.y, pb.y);  // kap odd : x1
                }
            #pragma unroll
            for (int i = 0; i < 2; ++i) {
                union { bf16x8 v; uint4 u; } a; a.u = af[i][sk];
                #pragma unroll
                for (int j = 0; j < 2; ++j)
                    acc[i][j] = __builtin_amdgcn_mfma_f32_32x32x16_bf16(
                        a.v, bfa[j].v, (sk == 0) ? zf : acc[i][j], 0, 0, 0);
            }
        }
        __builtin_amdgcn_s_setprio(0);
    }

    // write P (final T, bf16, uint16 index c*64+r) into slab back-halves
    {
        const int p = b * NSEG + seg;                    // 0..1023 per side
        char* pdst = wbuf + (size_t)(p >> 1) * SLAB_BYTES + PACK_BYTES + (p & 1) * 8192;
        #pragma unroll
        for (int i = 0; i < 2; ++i)
            #pragma unroll
            for (int j = 0; j < 2; ++j) {
                const int c = 32 * j + m5;
                #pragma unroll
                for (int Q = 0; Q < 4; ++Q) {
                    const int r0 = 32 * i + 8 * Q + 4 * H;
                    uint2 val;
                    val.x = pk2(acc[i][j][4 * Q + 0], acc[i][j][4 * Q + 1]);
                    val.y = pk2(acc[i][j][4 * Q + 2], acc[i][j][4 * Q + 3]);
                    *(uint2*)(pdst + c * 128 + r0 * 2) = val;
                }
            }
    }
    asm volatile("s_waitcnt vmcnt(0)" ::: "memory");   // drain dummy DMA before endpgm
}

// ---------------------------------------------------------------------------
// FUSED stage2+finalize (r13, measured-good): 64 blocks x 512 threads.
// ---------------------------------------------------------------------------
__global__ __launch_bounds__(512) void tail_kernel(
        const char* __restrict__ dl, const char* __restrict__ dr,
        const float* __restrict__ core, float* __restrict__ out) {
    const int b    = blockIdx.x;
    const int tid  = threadIdx.x;
    const int side = tid >> 8;
    const int r    = tid & 63;
    const int cg   = (tid >> 6) & 3;
    const char* wbuf = side ? dr : dl;

    __shared__ float vsh[2][DD];
    __shared__ float part[2][4][DD];
    if ((tid & 255) < DD) vsh[side][r] = (r == 0) ? 1.f : 0.f;

    auto Pseg = [&](int gi) -> const uint16_t* {
        const int g = side ? (NSEG - 1 - gi) : gi;
        const int p = b * NSEG + g;
        return (const uint16_t*)(wbuf
            + (size_t)(p >> 1) * SLAB_BYTES + PACK_BYTES + (p & 1) * 8192);
    };

    float pv[16];
    {
        const uint16_t* P = Pseg(0);
        #pragma unroll
        for (int cc = 0; cc < 16; ++cc)
            pv[cc] = __uint_as_float(((uint32_t)P[(cg * 16 + cc) * 64 + r]) << 16);
    }
    __syncthreads();

    for (int gi = 0; gi < NSEG; ++gi) {
        float nv[16];
        const bool more = (gi + 1 < NSEG);
        if (more) {
            const uint16_t* Pn = Pseg(gi + 1);          // issue early; waited at copy
            #pragma unroll
            for (int cc = 0; cc < 16; ++cc)
                nv[cc] = __uint_as_float(((uint32_t)Pn[(cg * 16 + cc) * 64 + r]) << 16);
        }
        float acc = 0.f;
        #pragma unroll
        for (int cc = 0; cc < 16; ++cc)
            acc = fmaf(vsh[side][cg * 16 + cc], pv[cc], acc);
        part[side][cg][r] = acc;
        asm volatile("s_waitcnt lgkmcnt(0)" ::: "memory");
        __builtin_amdgcn_s_barrier();
        if ((tid & 255) < DD)
            vsh[side][r] = part[side][0][r] + part[side][1][r]
                         + part[side][2][r] + part[side][3][r];
        asm volatile("s_waitcnt lgkmcnt(0)" ::: "memory");
        __builtin_amdgcn_s_barrier();
        if (more) {
            #pragma unroll
            for (int cc = 0; cc < 16; ++cc) pv[cc] = nv[cc];
        }
    }
    const int wv   = tid >> 6;
    const int lane = tid & 63;
    const float wrv = vsh[1][lane];
    for (int o = wv; o < NO; o += 8) {
        float acc = 0.f;
        #pragma unroll 8
        for (int l = 0; l < DD; ++l)
            acc += vsh[0][l] * core[(o * DD + l) * DD + lane];
        acc *= wrv;
        #pragma unroll
        for (int off = 32; off > 0; off >>= 1)
            acc += __shfl_xor(acc, off, 64);
        if (lane == 0) out[b * NO + o] = acc;
    }
}

extern "C" void kernel_launch(void* const* d_in, const int* in_sizes, int n_in,
                              void* d_out, int out_size, void* d_ws, size_t ws_size,
                              hipStream_t stream) {
    const float* x    = (const float*)d_in[0];   // [64][1024][2]
    float*       wl   = (float*)d_in[1];         // [512][64][64][2] fp32
    const float* core = (const float*)d_in[2];   // [10][64][64]
    float*       wr   = (float*)d_in[3];

    char* dl;
    char* dr;
    if (ws_size >= (size_t)WS_NEED) {   // keep inputs pristine when possible
        dl = (char*)d_ws;
        dr = dl + (size_t)NSITE * SLAB_BYTES;
    } else {                             // fallback: in-place
        dl = (char*)wl;
        dr = (char*)wr;
    }

    pack_kernel<<<2 * NSITE, 256, 0, stream>>>(wl, wr, dl, dr);
    stage1_kernel<<<2048, 64, 0, stream>>>(x, dl, dr);
    tail_kernel<<<NB, 512, 0, stream>>>(dl, dr, core, (float*)d_out);
}